// Round 2
// baseline (297.297 us; speedup 1.0000x reference)
//
#include <hip/hip_runtime.h>
#include <hip/hip_bf16.h>

typedef __attribute__((ext_vector_type(8))) short bf16x8;
typedef __attribute__((ext_vector_type(4))) float f32x4;
typedef unsigned short u16;
typedef unsigned int u32;

#define S_LEN 2048
#define HD 64
#define NH 16

__device__ __forceinline__ u16 f2bf(float x) {
  __hip_bfloat16 h = __float2bfloat16(x);   // RNE; compiler emits v_cvt_pk path
  return __builtin_bit_cast(u16, h);
}

// ushort-index swizzle for tiles with 64-ushort (128B) rows:
// byte ^= ((row&7)<<4)  ->  idx ^= ((row&7)<<3)
__device__ __forceinline__ int swz(int idx) {
  return idx ^ (((idx >> 6) & 7) << 3);
}

// Fused prep: K -> bf16 (vec4), V -> bf16 transposed VT[b][d][kv]
__global__ void prep(const float* __restrict__ K, const float* __restrict__ V,
                     u16* __restrict__ Kb, u16* __restrict__ VTb) {
  int i = blockIdx.x * 256 + threadIdx.x;
  if (i < 65536) {                       // K: 262144 elems as ushort4
    float4 v = reinterpret_cast<const float4*>(K)[i];
    ushort4 o;
    o.x = f2bf(v.x); o.y = f2bf(v.y); o.z = f2bf(v.z); o.w = f2bf(v.w);
    reinterpret_cast<ushort4*>(Kb)[i] = o;
  } else {
    int j = i - 65536;                   // VT element, coalesced writes
    int kv = j & (S_LEN - 1);
    int r = j >> 11;
    int d = r & 63;
    int b = r >> 6;
    VTb[j] = f2bf(V[((size_t)(b * S_LEN + kv)) * HD + d]);
  }
}

__launch_bounds__(256, 4)
__global__ void attn_fwd(const float* __restrict__ Q, const u16* __restrict__ Kb,
                         const u16* __restrict__ VTb, float* __restrict__ out) {
  __shared__ u16 Pl[4][16 * 64];         // per-wave P buffer only (8 KB)

  const int tid = threadIdx.x;
  const int w = tid >> 6;
  const int l = tid & 63;
  const int c = l & 15;
  const int g = l >> 4;

  const int bh = blockIdx.x >> 5;
  const int qt = blockIdx.x & 31;
  const int b = bh >> 4;
  const int q0 = qt * 64 + w * 16;

  // ---- Q fragments: convert fp32 -> bf16 in-register, scale folded with log2e
  // scores end up in log2 units: S_log2 = (QK^T)*(1/8)*log2(e); p = exp2(S-m)
  const float qs = 0.125f * 1.44269504f;
  bf16x8 qf[2];
  {
    const float* qrow = Q + ((size_t)(bh * S_LEN + q0 + c)) * HD + 8 * g;
    float4 a0 = *reinterpret_cast<const float4*>(qrow);
    float4 a1 = *reinterpret_cast<const float4*>(qrow + 4);
    float4 b0 = *reinterpret_cast<const float4*>(qrow + 32);
    float4 b1 = *reinterpret_cast<const float4*>(qrow + 36);
    qf[0][0] = f2bf(a0.x * qs); qf[0][1] = f2bf(a0.y * qs);
    qf[0][2] = f2bf(a0.z * qs); qf[0][3] = f2bf(a0.w * qs);
    qf[0][4] = f2bf(a1.x * qs); qf[0][5] = f2bf(a1.y * qs);
    qf[0][6] = f2bf(a1.z * qs); qf[0][7] = f2bf(a1.w * qs);
    qf[1][0] = f2bf(b0.x * qs); qf[1][1] = f2bf(b0.y * qs);
    qf[1][2] = f2bf(b0.z * qs); qf[1][3] = f2bf(b0.w * qs);
    qf[1][4] = f2bf(b1.x * qs); qf[1][5] = f2bf(b1.y * qs);
    qf[1][6] = f2bf(b1.z * qs); qf[1][7] = f2bf(b1.w * qs);
  }

  f32x4 oa[4];
  #pragma unroll
  for (int cb = 0; cb < 4; ++cb) oa[cb] = (f32x4){0.f, 0.f, 0.f, 0.f};
  float m_r[4] = {-1e30f, -1e30f, -1e30f, -1e30f};
  float l_r[4] = {0.f, 0.f, 0.f, 0.f};

  const u16* Kbase = Kb + (size_t)b * S_LEN * HD;
  const u16* Vbase = VTb + (size_t)b * HD * S_LEN;

  for (int kv0 = 0; kv0 < S_LEN; kv0 += 64) {
    // ---- K fragments direct from global (L2-hit; 16 consecutive 128B rows per cb)
    bf16x8 kf0[4], kf1[4];
    #pragma unroll
    for (int cb = 0; cb < 4; ++cb) {
      const u16* kr = Kbase + (size_t)(kv0 + 16 * cb + c) * HD + 8 * g;
      kf0[cb] = *reinterpret_cast<const bf16x8*>(kr);
      kf1[cb] = *reinterpret_cast<const bf16x8*>(kr + 32);
    }

    // ---- S = Q K^T (in log2 units)
    f32x4 sa[4];
    #pragma unroll
    for (int cb = 0; cb < 4; ++cb) {
      f32x4 z = (f32x4){0.f, 0.f, 0.f, 0.f};
      z = __builtin_amdgcn_mfma_f32_16x16x32_bf16(qf[0], kf0[cb], z, 0, 0, 0);
      sa[cb] = __builtin_amdgcn_mfma_f32_16x16x32_bf16(qf[1], kf1[cb], z, 0, 0, 0);
    }

    // ---- V^T fragments (issue early; latency hides under softmax)
    bf16x8 vf0[4], vf1[4];
    #pragma unroll
    for (int cb = 0; cb < 4; ++cb) {
      const u16* vr = Vbase + (size_t)(16 * cb + c) * S_LEN + kv0 + 8 * g;
      vf0[cb] = *reinterpret_cast<const bf16x8*>(vr);
      vf1[cb] = *reinterpret_cast<const bf16x8*>(vr + 32);
    }

    // ---- online softmax, row r of wave = q0 + 4*g + r
    float mt[4];
    #pragma unroll
    for (int r = 0; r < 4; ++r)
      mt[r] = fmaxf(fmaxf(sa[0][r], sa[1][r]), fmaxf(sa[2][r], sa[3][r]));
    #pragma unroll
    for (int off = 8; off >= 1; off >>= 1) {
      #pragma unroll
      for (int r = 0; r < 4; ++r)
        mt[r] = fmaxf(mt[r], __shfl_xor(mt[r], off));
    }

    // T13 defer-max: skip m-update + O-rescale unless max grew by >8 (log2)
    int need = (mt[0] > m_r[0] + 8.f) | (mt[1] > m_r[1] + 8.f) |
               (mt[2] > m_r[2] + 8.f) | (mt[3] > m_r[3] + 8.f);
    if (__any(need)) {
      #pragma unroll
      for (int r = 0; r < 4; ++r) {
        float mn = fmaxf(m_r[r], mt[r]);
        float corr = exp2f(m_r[r] - mn);
        m_r[r] = mn;
        l_r[r] *= corr;
        oa[0][r] *= corr; oa[1][r] *= corr; oa[2][r] *= corr; oa[3][r] *= corr;
      }
    }

    float rs[4] = {0.f, 0.f, 0.f, 0.f};
    #pragma unroll
    for (int cb = 0; cb < 4; ++cb) {
      #pragma unroll
      for (int r = 0; r < 4; ++r) {
        float p = exp2f(sa[cb][r] - m_r[r]);   // bounded by 2^8
        rs[r] += p;
        Pl[w][swz((4 * g + r) * 64 + 16 * cb + c)] = f2bf(p);
      }
    }
    #pragma unroll
    for (int off = 8; off >= 1; off >>= 1) {
      #pragma unroll
      for (int r = 0; r < 4; ++r)
        rs[r] += __shfl_xor(rs[r], off);
    }
    #pragma unroll
    for (int r = 0; r < 4; ++r) l_r[r] += rs[r];

    // ---- O += P V (A = P via per-wave LDS; no barrier needed: same wave)
    bf16x8 pf0 = *reinterpret_cast<const bf16x8*>(&Pl[w][swz(c * 64 + 8 * g)]);
    bf16x8 pf1 = *reinterpret_cast<const bf16x8*>(&Pl[w][swz(c * 64 + 32 + 8 * g)]);
    #pragma unroll
    for (int cb = 0; cb < 4; ++cb) {
      oa[cb] = __builtin_amdgcn_mfma_f32_16x16x32_bf16(pf0, vf0[cb], oa[cb], 0, 0, 0);
      oa[cb] = __builtin_amdgcn_mfma_f32_16x16x32_bf16(pf1, vf1[cb], oa[cb], 0, 0, 0);
    }
  }

  // ---- epilogue
  #pragma unroll
  for (int r = 0; r < 4; ++r) {
    float inv = 1.0f / l_r[r];
    #pragma unroll
    for (int cb = 0; cb < 4; ++cb)
      out[((size_t)(bh * S_LEN + q0 + 4 * g + r)) * HD + 16 * cb + c] = oa[cb][r] * inv;
  }
}

extern "C" void kernel_launch(void* const* d_in, const int* in_sizes, int n_in,
                              void* d_out, int out_size, void* d_ws, size_t ws_size,
                              hipStream_t stream) {
  const float* Q = (const float*)d_in[0];
  const float* K = (const float*)d_in[1];
  const float* V = (const float*)d_in[2];
  float* out = (float*)d_out;

  const int KN = 2 * S_LEN * HD;   // 262,144
  u16* Kb  = (u16*)d_ws;
  u16* VTb = Kb + KN;

  hipLaunchKernelGGL(prep, dim3((65536 + KN) / 256), dim3(256), 0, stream,
                     K, V, Kb, VTb);
  hipLaunchKernelGGL(attn_fwd, dim3(1024), dim3(256), 0, stream, Q, Kb, VTb, out);
}

// Round 4
// 176.004 us; speedup vs baseline: 1.6891x; 1.6891x over previous
//
#include <hip/hip_runtime.h>
#include <hip/hip_bf16.h>

typedef __attribute__((ext_vector_type(8))) short bf16x8;
typedef __attribute__((ext_vector_type(4))) float f32x4;
typedef unsigned short u16;
typedef unsigned int u32;

#define S_LEN 2048
#define HD 64
#define NH 16

__device__ __forceinline__ u16 f2bf(float x) {
  __hip_bfloat16 h = __float2bfloat16(x);
  return __builtin_bit_cast(u16, h);
}

// ushort-index swizzle for tiles with 64-ushort (128B) rows:
// byte ^= ((row&7)<<4)  ->  ushort idx ^= ((row&7)<<3)
__device__ __forceinline__ int swz(int idx) {
  return idx ^ (((idx >> 6) & 7) << 3);
}

// async global->LDS, 16B per lane; LDS base must be wave-uniform
__device__ __forceinline__ void gload16(const u16* g, u16* lds) {
  __builtin_amdgcn_global_load_lds(
      (const __attribute__((address_space(1))) u32*)g,
      (__attribute__((address_space(3))) u32*)lds, 16, 0, 0);
}

// Fused prep: K -> bf16 (vec4), V -> bf16 transposed VT[b][d][kv]
__global__ void prep(const float* __restrict__ K, const float* __restrict__ V,
                     u16* __restrict__ Kb, u16* __restrict__ VTb) {
  int i = blockIdx.x * 256 + threadIdx.x;
  if (i < 65536) {                       // K: 262144 elems as ushort4
    float4 v = reinterpret_cast<const float4*>(K)[i];
    ushort4 o;
    o.x = f2bf(v.x); o.y = f2bf(v.y); o.z = f2bf(v.z); o.w = f2bf(v.w);
    reinterpret_cast<ushort4*>(Kb)[i] = o;
  } else {
    int j = i - 65536;                   // VT element, coalesced writes
    int kv = j & (S_LEN - 1);
    int r = j >> 11;
    int d = r & 63;
    int b = r >> 6;
    VTb[j] = f2bf(V[((size_t)(b * S_LEN + kv)) * HD + d]);
  }
}

__launch_bounds__(256, 4)
__global__ void attn_fwd(const float* __restrict__ Q, const u16* __restrict__ Kb,
                         const u16* __restrict__ VTb, float* __restrict__ out) {
  __shared__ u16 Kt[2][64 * 64];     // 16 KB double-buffered K tile
  __shared__ u16 VTt[2][64 * 64];    // 16 KB double-buffered V^T tile
  __shared__ u16 Pl[4][16 * 64];     // 8 KB per-wave P buffer

  const int tid = threadIdx.x;
  const int w = tid >> 6;
  const int l = tid & 63;
  const int c = l & 15;
  const int g = l >> 4;

  const int bh = blockIdx.x >> 5;
  const int qt = blockIdx.x & 31;
  const int b = bh >> 4;
  const int q0 = qt * 64 + w * 16;

  const u16* Kbase = Kb + (size_t)b * S_LEN * HD;
  const u16* Vbase = VTb + (size_t)b * HD * S_LEN;

  // staging geometry: wave w stages rows 16w..16w+15 of each 64-row tile,
  // as 2 issues of 8 rows (64 lanes x 16B = 1KB). LDS dest is LINEAR;
  // source chunk index pre-XOR'd so reads can use swz() (rule #21).
  const int srow = l >> 3;                 // 0..7 within 8-row block
  const int sch = (l & 7) ^ srow;          // pre-swizzled 16B chunk 0..7

  // ---- Q fragments: fp32 -> bf16 in-register; 1/8 scale and log2e folded.
  // scores come out in log2 units: p = exp2(s - m)
  const float qs = 0.125f * 1.44269504f;
  bf16x8 qf[2];
  {
    const float* qrow = Q + ((size_t)(bh * S_LEN + q0 + c)) * HD + 8 * g;
    float4 a0 = *reinterpret_cast<const float4*>(qrow);
    float4 a1 = *reinterpret_cast<const float4*>(qrow + 4);
    float4 b0 = *reinterpret_cast<const float4*>(qrow + 32);
    float4 b1 = *reinterpret_cast<const float4*>(qrow + 36);
    qf[0][0] = f2bf(a0.x * qs); qf[0][1] = f2bf(a0.y * qs);
    qf[0][2] = f2bf(a0.z * qs); qf[0][3] = f2bf(a0.w * qs);
    qf[0][4] = f2bf(a1.x * qs); qf[0][5] = f2bf(a1.y * qs);
    qf[0][6] = f2bf(a1.z * qs); qf[0][7] = f2bf(a1.w * qs);
    qf[1][0] = f2bf(b0.x * qs); qf[1][1] = f2bf(b0.y * qs);
    qf[1][2] = f2bf(b0.z * qs); qf[1][3] = f2bf(b0.w * qs);
    qf[1][4] = f2bf(b1.x * qs); qf[1][5] = f2bf(b1.y * qs);
    qf[1][6] = f2bf(b1.z * qs); qf[1][7] = f2bf(b1.w * qs);
  }

  f32x4 oa[4];
  #pragma unroll
  for (int cb = 0; cb < 4; ++cb) oa[cb] = (f32x4){0.f, 0.f, 0.f, 0.f};
  float m_r[4] = {-1e30f, -1e30f, -1e30f, -1e30f};
  float l_r[4] = {0.f, 0.f, 0.f, 0.f};

  // ---- prologue: stage tile 0 into buf 0
  #pragma unroll
  for (int h = 0; h < 2; ++h) {
    int r0 = 16 * w + 8 * h;
    int row = r0 + srow;
    gload16(Kbase + (size_t)row * HD + sch * 8, &Kt[0][r0 * 64]);
    gload16(Vbase + (size_t)row * S_LEN + sch * 8, &VTt[0][r0 * 64]);
  }
  __syncthreads();

  int cur = 0;
  for (int t = 0; t < 32; ++t) {
    // ---- issue next tile's stage FIRST (loads fly during compute)
    if (t != 31) {
      int kv1 = (t + 1) * 64;
      #pragma unroll
      for (int h = 0; h < 2; ++h) {
        int r0 = 16 * w + 8 * h;
        int row = r0 + srow;
        gload16(Kbase + (size_t)(kv1 + row) * HD + sch * 8, &Kt[cur ^ 1][r0 * 64]);
        gload16(Vbase + (size_t)row * S_LEN + kv1 + sch * 8, &VTt[cur ^ 1][r0 * 64]);
      }
    }

    // ---- S = Q K^T (log2 units), K frags from LDS
    f32x4 sa[4];
    #pragma unroll
    for (int cb = 0; cb < 4; ++cb) {
      bf16x8 k0 = *reinterpret_cast<const bf16x8*>(&Kt[cur][swz((16 * cb + c) * 64 + 8 * g)]);
      bf16x8 k1 = *reinterpret_cast<const bf16x8*>(&Kt[cur][swz((16 * cb + c) * 64 + 32 + 8 * g)]);
      f32x4 z = (f32x4){0.f, 0.f, 0.f, 0.f};
      z = __builtin_amdgcn_mfma_f32_16x16x32_bf16(qf[0], k0, z, 0, 0, 0);
      sa[cb] = __builtin_amdgcn_mfma_f32_16x16x32_bf16(qf[1], k1, z, 0, 0, 0);
    }

    // ---- online softmax; row r of wave = q0 + 4*g + r
    float mt[4];
    #pragma unroll
    for (int r = 0; r < 4; ++r)
      mt[r] = fmaxf(fmaxf(sa[0][r], sa[1][r]), fmaxf(sa[2][r], sa[3][r]));
    #pragma unroll
    for (int off = 8; off >= 1; off >>= 1) {
      #pragma unroll
      for (int r = 0; r < 4; ++r)
        mt[r] = fmaxf(mt[r], __shfl_xor(mt[r], off));
    }

    // T13 defer-max: skip m-update + O-rescale unless max grew by >8 (log2)
    int need = (mt[0] > m_r[0] + 8.f) | (mt[1] > m_r[1] + 8.f) |
               (mt[2] > m_r[2] + 8.f) | (mt[3] > m_r[3] + 8.f);
    if (__any(need)) {
      #pragma unroll
      for (int r = 0; r < 4; ++r) {
        float mn = fmaxf(m_r[r], mt[r]);
        float corr = exp2f(m_r[r] - mn);
        m_r[r] = mn;
        l_r[r] *= corr;
        oa[0][r] *= corr; oa[1][r] *= corr; oa[2][r] *= corr; oa[3][r] *= corr;
      }
    }

    float rs[4] = {0.f, 0.f, 0.f, 0.f};
    #pragma unroll
    for (int cb = 0; cb < 4; ++cb) {
      #pragma unroll
      for (int r = 0; r < 4; ++r) {
        float p = exp2f(sa[cb][r] - m_r[r]);     // bounded by 2^8
        rs[r] += p;
        Pl[w][swz((4 * g + r) * 64 + 16 * cb + c)] = f2bf(p);
      }
    }
    #pragma unroll
    for (int off = 8; off >= 1; off >>= 1) {
      #pragma unroll
      for (int r = 0; r < 4; ++r)
        rs[r] += __shfl_xor(rs[r], off);
    }
    #pragma unroll
    for (int r = 0; r < 4; ++r) l_r[r] += rs[r];

    // ---- O += P V (A = P via per-wave LDS; same-wave, no barrier)
    bf16x8 pf0 = *reinterpret_cast<const bf16x8*>(&Pl[w][swz(c * 64 + 8 * g)]);
    bf16x8 pf1 = *reinterpret_cast<const bf16x8*>(&Pl[w][swz(c * 64 + 32 + 8 * g)]);
    #pragma unroll
    for (int cb = 0; cb < 4; ++cb) {
      bf16x8 v0 = *reinterpret_cast<const bf16x8*>(&VTt[cur][swz((16 * cb + c) * 64 + 8 * g)]);
      bf16x8 v1 = *reinterpret_cast<const bf16x8*>(&VTt[cur][swz((16 * cb + c) * 64 + 32 + 8 * g)]);
      oa[cb] = __builtin_amdgcn_mfma_f32_16x16x32_bf16(pf0, v0, oa[cb], 0, 0, 0);
      oa[cb] = __builtin_amdgcn_mfma_f32_16x16x32_bf16(pf1, v1, oa[cb], 0, 0, 0);
    }

    // one barrier per tile; its implicit vmcnt(0) drains the prefetch,
    // which has had the whole compute phase to land
    __syncthreads();
    cur ^= 1;
  }

  // ---- epilogue
  #pragma unroll
  for (int r = 0; r < 4; ++r) {
    float inv = 1.0f / l_r[r];
    #pragma unroll
    for (int cb = 0; cb < 4; ++cb)
      out[((size_t)(bh * S_LEN + q0 + 4 * g + r)) * HD + 16 * cb + c] = oa[cb][r] * inv;
  }
}

extern "C" void kernel_launch(void* const* d_in, const int* in_sizes, int n_in,
                              void* d_out, int out_size, void* d_ws, size_t ws_size,
                              hipStream_t stream) {
  const float* Q = (const float*)d_in[0];
  const float* K = (const float*)d_in[1];
  const float* V = (const float*)d_in[2];
  float* out = (float*)d_out;

  const int KN = 2 * S_LEN * HD;   // 262,144
  u16* Kb  = (u16*)d_ws;
  u16* VTb = Kb + KN;

  hipLaunchKernelGGL(prep, dim3((65536 + KN) / 256), dim3(256), 0, stream,
                     K, V, Kb, VTb);
  hipLaunchKernelGGL(attn_fwd, dim3(1024), dim3(256), 0, stream, Q, Kb, VTb, out);
}

// Round 6
// 140.069 us; speedup vs baseline: 2.1225x; 1.2566x over previous
//
#include <hip/hip_runtime.h>
#include <hip/hip_bf16.h>

typedef __attribute__((ext_vector_type(8))) short bf16x8;
typedef __attribute__((ext_vector_type(4))) short bf16x4;
typedef __attribute__((ext_vector_type(16))) float f32x16;
typedef unsigned short u16;
typedef unsigned int u32;

#define S_LEN 2048
#define HD 64

__device__ __forceinline__ u16 f2bf(float x) {
  __hip_bfloat16 h = __float2bfloat16(x);
  return __builtin_bit_cast(u16, h);
}

// pack two floats to bf16 pair (lo -> bits 0..15, hi -> bits 16..31)
__device__ __forceinline__ u32 pk2(float lo, float hi) {
  return ((u32)f2bf(hi) << 16) | (u32)f2bf(lo);
}

// ushort-index swizzle for tiles with 64-ushort (128B) rows: byte ^= ((row&7)<<4)
__device__ __forceinline__ int swz(int idx) {
  return idx ^ (((idx >> 6) & 7) << 3);
}

__device__ __forceinline__ void gload16(const u16* g, u16* lds) {
  __builtin_amdgcn_global_load_lds(
      (const __attribute__((address_space(1))) u32*)g,
      (__attribute__((address_space(3))) u32*)lds, 16, 0, 0);
}

#if __has_builtin(__builtin_amdgcn_mfma_f32_32x32x8bf16_1k)
__device__ __forceinline__ f32x16 mfma8(bf16x4 a, bf16x4 b, f32x16 c) {
  return __builtin_amdgcn_mfma_f32_32x32x8bf16_1k(a, b, c, 0, 0, 0);
}
#else
__device__ __forceinline__ f32x16 mfma8(bf16x4 a, bf16x4 b, f32x16 c) {
  asm volatile("v_mfma_f32_32x32x8_bf16 %0, %1, %2, %0\n\ts_nop 7\n\ts_nop 7"
               : "+v"(c) : "v"(a), "v"(b));
  return c;
}
#endif

// Fused prep: K -> bf16 (vec4), V -> bf16 transposed VT[b][d][kv]
__global__ void prep(const float* __restrict__ K, const float* __restrict__ V,
                     u16* __restrict__ Kb, u16* __restrict__ VTb) {
  int i = blockIdx.x * 256 + threadIdx.x;
  if (i < 65536) {
    float4 v = reinterpret_cast<const float4*>(K)[i];
    ushort4 o;
    o.x = f2bf(v.x); o.y = f2bf(v.y); o.z = f2bf(v.z); o.w = f2bf(v.w);
    reinterpret_cast<ushort4*>(Kb)[i] = o;
  } else {
    int j = i - 65536;
    int kv = j & (S_LEN - 1);
    int r = j >> 11;
    int d = r & 63;
    int b = r >> 6;
    VTb[j] = f2bf(V[((size_t)(b * S_LEN + kv)) * HD + d]);
  }
}

// Swapped-QK^T flash attention, P fully in-lane.
// QK^T: mfma_f32_32x32x16_bf16, S^T acc: col=q(lane&31), kv=(r&3)+8(r>>2)+4hi.
// PV:   mfma_f32_32x32x8_bf16; its A-layout (k=4hi+j) matches the S^T acc
//       layout exactly -> P fragments are built in-lane (no cross-lane moves).
__launch_bounds__(256, 2)
__global__ void attn_fwd(const float* __restrict__ Q, const u16* __restrict__ Kb,
                         const u16* __restrict__ VTb, float* __restrict__ out) {
  __shared__ u16 Kt[2][64 * 64];    // [kv][d] 8KB x2
  __shared__ u16 VTt[2][64 * 64];   // [d][kv] 8KB x2

  const int tid = threadIdx.x;
  const int w = tid >> 6;
  const int lane = tid & 63;
  const int q = lane & 31;          // q-row for QK/PV-A; d-col for PV output
  const int hi = lane >> 5;

  const int bh = blockIdx.x >> 4;       // 0..31
  const int qt = blockIdx.x & 15;       // 0..15
  const int b = bh >> 4;
  const int q0w = qt * 128 + w * 32;

  const u16* Kbase = Kb + (size_t)b * S_LEN * HD;
  const u16* Vbase = VTb + (size_t)b * HD * S_LEN;

  const int sr = lane >> 3;              // staging row within 8-row block
  const int cs = (lane & 7) ^ sr;        // pre-swizzled 16B chunk

  // ---- Q fragments (B-operand): lane holds Q[q0w+q][16s+8hi+j], scaled
  const float qs = 0.125f * 1.44269504f;   // 1/sqrt(64) * log2(e)
  bf16x8 qreg[4];
  {
    const float* qrow = Q + ((size_t)(bh * S_LEN + q0w + q)) * HD + 8 * hi;
    #pragma unroll
    for (int s = 0; s < 4; ++s) {
      float4 f0 = *reinterpret_cast<const float4*>(qrow + 16 * s);
      float4 f1 = *reinterpret_cast<const float4*>(qrow + 16 * s + 4);
      bf16x8 v;
      v[0] = f2bf(f0.x * qs); v[1] = f2bf(f0.y * qs);
      v[2] = f2bf(f0.z * qs); v[3] = f2bf(f0.w * qs);
      v[4] = f2bf(f1.x * qs); v[5] = f2bf(f1.y * qs);
      v[6] = f2bf(f1.z * qs); v[7] = f2bf(f1.w * qs);
      qreg[s] = v;
    }
  }

  f32x16 oacc0, oacc1;
  #pragma unroll
  for (int i = 0; i < 16; ++i) { oacc0[i] = 0.f; oacc1[i] = 0.f; }
  float m = -1e30f, l = 0.f;

  // ---- prologue: stage tile 0 into buf 0
  #pragma unroll
  for (int h = 0; h < 2; ++h) {
    int row = h * 32 + w * 8 + sr;
    gload16(Kbase + (size_t)row * HD + cs * 8, &Kt[0][h * 2048 + w * 512]);
    gload16(Vbase + (size_t)row * S_LEN + cs * 8, &VTt[0][h * 2048 + w * 512]);
  }
  __syncthreads();

  int cur = 0;
  for (int t = 0; t < 32; ++t) {
    // ---- issue next tile's stage first (flies during compute)
    if (t != 31) {
      int kv1 = (t + 1) * 64;
      #pragma unroll
      for (int h = 0; h < 2; ++h) {
        int row = h * 32 + w * 8 + sr;
        gload16(Kbase + (size_t)(kv1 + row) * HD + cs * 8,
                &Kt[cur ^ 1][h * 2048 + w * 512]);
        gload16(Vbase + (size_t)row * S_LEN + kv1 + cs * 8,
                &VTt[cur ^ 1][h * 2048 + w * 512]);
      }
    }

    // ---- S^T = K Q^T (log2 units)
    f32x16 s0, s1;
    #pragma unroll
    for (int i = 0; i < 16; ++i) { s0[i] = 0.f; s1[i] = 0.f; }
    __builtin_amdgcn_s_setprio(1);
    #pragma unroll
    for (int s = 0; s < 4; ++s) {
      bf16x8 k0 = *reinterpret_cast<const bf16x8*>(&Kt[cur][swz(q * 64 + 16 * s + 8 * hi)]);
      bf16x8 k1 = *reinterpret_cast<const bf16x8*>(&Kt[cur][swz((32 + q) * 64 + 16 * s + 8 * hi)]);
      s0 = __builtin_amdgcn_mfma_f32_32x32x16_bf16(k0, qreg[s], s0, 0, 0, 0);
      s1 = __builtin_amdgcn_mfma_f32_32x32x16_bf16(k1, qreg[s], s1, 0, 0, 0);
    }
    __builtin_amdgcn_s_setprio(0);

    // ---- softmax: in-lane max (32 vals) + one cross-half shfl
    float pm = s0[0];
    #pragma unroll
    for (int i = 1; i < 16; ++i) pm = fmaxf(pm, s0[i]);
    #pragma unroll
    for (int i = 0; i < 16; ++i) pm = fmaxf(pm, s1[i]);
    pm = fmaxf(pm, __shfl_xor(pm, 32));

    // T13 defer-max (log2 domain, THR=8)
    if (__any(pm > m + 8.f)) {
      float mn = fmaxf(m, pm);
      float corr = exp2f(m - mn);
      m = mn;
      l *= corr;
      #pragma unroll
      for (int r = 0; r < 16; ++r) {
        int qr = (r & 3) + 8 * (r >> 2) + 4 * hi;
        float cr = __shfl(corr, qr);   // corr for q-row qr (same both halves)
        oacc0[r] *= cr;
        oacc1[r] *= cr;
      }
    }

    // ---- P = exp2(S - m); partial row-sum
    float p0[16], p1[16];
    float la = 0.f;
    #pragma unroll
    for (int i = 0; i < 16; ++i) { p0[i] = exp2f(s0[i] - m); la += p0[i]; }
    #pragma unroll
    for (int i = 0; i < 16; ++i) { p1[i] = exp2f(s1[i] - m); la += p1[i]; }
    l += la;

    // ---- O += P V : A = P in-lane (32x32x8), B = V via VT tile
    union PW { u32 w[2]; bf16x4 v; };
    __builtin_amdgcn_s_setprio(1);
    #pragma unroll
    for (int t8 = 0; t8 < 8; ++t8) {
      PW pa;
      if (t8 < 4) {
        pa.w[0] = pk2(p0[4 * t8], p0[4 * t8 + 1]);
        pa.w[1] = pk2(p0[4 * t8 + 2], p0[4 * t8 + 3]);
      } else {
        int u = 4 * (t8 - 4);
        pa.w[0] = pk2(p1[u], p1[u + 1]);
        pa.w[1] = pk2(p1[u + 2], p1[u + 3]);
      }
      bf16x4 v0 = *reinterpret_cast<const bf16x4*>(&VTt[cur][swz(q * 64 + 8 * t8 + 4 * hi)]);
      bf16x4 v1 = *reinterpret_cast<const bf16x4*>(&VTt[cur][swz((32 + q) * 64 + 8 * t8 + 4 * hi)]);
      oacc0 = mfma8(pa.v, v0, oacc0);
      oacc1 = mfma8(pa.v, v1, oacc1);
    }
    __builtin_amdgcn_s_setprio(0);

    __syncthreads();     // drains vmcnt: next tile staged
    cur ^= 1;
  }

  // ---- epilogue: combine l across halves, normalize, coalesced stores
  float lt = l + __shfl_xor(l, 32);
  float invq = 1.0f / lt;
  #pragma unroll
  for (int r = 0; r < 16; ++r) {
    int qr = (r & 3) + 8 * (r >> 2) + 4 * hi;
    float iv = __shfl(invq, qr);
    size_t o = ((size_t)(bh * S_LEN + q0w + qr)) * HD + q;
    out[o] = oacc0[r] * iv;
    out[o + 32] = oacc1[r] * iv;
  }
}

extern "C" void kernel_launch(void* const* d_in, const int* in_sizes, int n_in,
                              void* d_out, int out_size, void* d_ws, size_t ws_size,
                              hipStream_t stream) {
  const float* Q = (const float*)d_in[0];
  const float* K = (const float*)d_in[1];
  const float* V = (const float*)d_in[2];
  float* out = (float*)d_out;

  const int KN = 2 * S_LEN * HD;   // 262,144
  u16* Kb = (u16*)d_ws;
  u16* VTb = Kb + KN;

  hipLaunchKernelGGL(prep, dim3((65536 + KN) / 256), dim3(256), 0, stream,
                     K, V, Kb, VTb);
  // 32 bh pairs x 16 q-tiles of 128 rows; 4 waves x 32 q each
  hipLaunchKernelGGL(attn_fwd, dim3(512), dim3(256), 0, stream, Q, Kb, VTb, out);
}